// Round 3
// baseline (179.098 us; speedup 1.0000x reference)
//
#include <hip/hip_runtime.h>
#include <hip/hip_fp16.h>
#include <math.h>

#define NB  4
#define DD  128
#define HH  128
#define WW  128
#define KS  11
#define PAD 5
#define TH  8                 // output rows per K2 block
#define RR  (TH + 2 * PAD)    // 18 staged W-conved rows
#define ZC  16                // z-chunk length in K1
#define ZCH (DD / ZC)         // 8 chunks

struct GW { float g[KS]; };

// ---------------------------------------------------------------------------
// K1: D-conv (along z) of the 5 raw fields (x, y, x2, y2, xy) straight from
// the images. Register shift-accumulator chain (55 regs, static indices),
// no LDS, no syncs. fp32 compute, fp16 store to A[f][n][z][h][w].
// grid = NB * ZCH * 64, block = 256 (2 h-rows x 128 w).
// ---------------------------------------------------------------------------
__global__ __launch_bounds__(256)
void k1_dconv(const float* __restrict__ img1, const float* __restrict__ img2,
              __half* __restrict__ A, GW gw) {
    const int t  = threadIdx.x;
    const int b  = blockIdx.x;
    const int hb = b & 63;
    const int zc = (b >> 6) & (ZCH - 1);
    const int n  = b >> 9;
    const int w  = t & 127;
    const int h  = hb * 2 + (t >> 7);
    const int c0 = zc * ZC;

    const long long FS    = (long long)NB * DD * HH * WW;
    const long long nBase = (long long)n * DD * HH * WW + (long long)h * WW + w;

    float acc[5][KS];
    #pragma unroll
    for (int f = 0; f < 5; ++f)
        #pragma unroll
        for (int j = 0; j < KS; ++j) acc[f][j] = 0.f;

    for (int s = 0; s < ZC + 2 * PAD; ++s) {
        const int zi = c0 - PAD + s;
        float x = 0.f, y = 0.f;
        if (zi >= 0 && zi < DD) {
            const long long off = nBase + (long long)zi * (HH * WW);
            x = img1[off];
            y = img2[off];
        }
        const float v[5] = {x, y, x * x, y * y, x * y};
        #pragma unroll
        for (int f = 0; f < 5; ++f) {
            #pragma unroll
            for (int j = KS - 1; j >= 1; --j)
                acc[f][j] = fmaf(gw.g[j], v[f], acc[f][j - 1]);
            acc[f][0] = gw.g[0] * v[f];
        }
        if (s >= 2 * PAD) {
            const int zo = zi - PAD;
            const long long ooff = nBase + (long long)zo * (HH * WW);
            #pragma unroll
            for (int f = 0; f < 5; ++f)
                A[f * FS + ooff] = __float2half(acc[f][KS - 1]);
        }
    }
}

// ---------------------------------------------------------------------------
// K2: W-conv + H-conv of the 5 D-conved fields (read from L3-resident fp16 A)
// + SSIM map + block reduction. LDS stages the W-conved tile as fp16
// ([5][18][128] = 23 KB -> 6 blocks/CU). Writes only one double per block.
// grid = NB * DD * 16, block = 256.
// ---------------------------------------------------------------------------
__global__ __launch_bounds__(256)
void k2_ssim(const __half* __restrict__ A, double* __restrict__ partials,
             GW gw) {
    __shared__ alignas(16) __half s_wc[5][RR][WW];   // 23,040 B
    __shared__ double red[256];
    const int b  = blockIdx.x;
    const int ht = b & 15;
    const int z  = (b >> 4) & (DD - 1);
    const int n  = b >> 11;
    const int t  = threadIdx.x;
    const int h0 = ht * TH;

    const long long FS = (long long)NB * DD * HH * WW;
    const long long planeBase = ((long long)(n * DD + z)) * (HH * WW);

    // ---- Phase W: 576 quad-tasks (18 rows x 32 w-quads) ----
    for (int task = t; task < RR * 32; task += 256) {
        const int r  = task >> 5;
        const int q  = task & 31;
        const int gh = h0 + r - PAD;
        const bool okh = (gh >= 0) && (gh < HH);

        #pragma unroll
        for (int f = 0; f < 5; ++f) {
            float a0 = 0.f, a1 = 0.f, a2 = 0.f, a3 = 0.f;
            if (okh) {
                const __half* base = A + f * FS + planeBase + (long long)gh * WW;
                float win[20];
                #pragma unroll
                for (int c = 0; c < 5; ++c) {
                    const int w4 = 4 * (q - 2 + c);
                    float2 f01 = make_float2(0.f, 0.f);
                    float2 f23 = make_float2(0.f, 0.f);
                    if (w4 >= 0 && w4 < WW) {
                        const __half2* hp =
                            reinterpret_cast<const __half2*>(base + w4);
                        f01 = __half22float2(hp[0]);
                        f23 = __half22float2(hp[1]);
                    }
                    win[4*c+0] = f01.x; win[4*c+1] = f01.y;
                    win[4*c+2] = f23.x; win[4*c+3] = f23.y;
                }
                #pragma unroll
                for (int k = 0; k < KS; ++k) {
                    const float g = gw.g[k];
                    a0 = fmaf(g, win[k + 3], a0);
                    a1 = fmaf(g, win[k + 4], a1);
                    a2 = fmaf(g, win[k + 5], a2);
                    a3 = fmaf(g, win[k + 6], a3);
                }
            }
            __half2* sp = reinterpret_cast<__half2*>(&s_wc[f][r][4 * q]);
            sp[0] = __float22half2_rn(make_float2(a0, a1));
            sp[1] = __float22half2_rn(make_float2(a2, a3));
        }
    }
    __syncthreads();

    // ---- Phase H: thread = (row p, w-quad q) ----
    const int p = t >> 5;
    const int q = t & 31;
    float acc[5][4];
    #pragma unroll
    for (int f = 0; f < 5; ++f)
        #pragma unroll
        for (int j = 0; j < 4; ++j) acc[f][j] = 0.f;

    #pragma unroll
    for (int k = 0; k < KS; ++k) {
        const float g = gw.g[k];
        #pragma unroll
        for (int f = 0; f < 5; ++f) {
            const __half2* sp =
                reinterpret_cast<const __half2*>(&s_wc[f][p + k][4 * q]);
            const float2 f01 = __half22float2(sp[0]);
            const float2 f23 = __half22float2(sp[1]);
            acc[f][0] = fmaf(g, f01.x, acc[f][0]);
            acc[f][1] = fmaf(g, f01.y, acc[f][1]);
            acc[f][2] = fmaf(g, f23.x, acc[f][2]);
            acc[f][3] = fmaf(g, f23.y, acc[f][3]);
        }
    }

    const float C1 = 1e-4f, C2 = 9e-4f;
    float sum = 0.f;
    #pragma unroll
    for (int j = 0; j < 4; ++j) {
        const float mu1 = acc[0][j], mu2 = acc[1][j];
        const float mu1s = mu1 * mu1, mu2s = mu2 * mu2, mu12 = mu1 * mu2;
        const float sg1  = acc[2][j] - mu1s;
        const float sg2  = acc[3][j] - mu2s;
        const float sg12 = acc[4][j] - mu12;
        const float num = (2.f * mu12 + C1) * (2.f * sg12 + C2);
        const float den = (mu1s + mu2s + C1) * (sg1 + sg2 + C2);
        sum += num / den;
    }

    red[t] = (double)sum;
    __syncthreads();
    for (int sft = 128; sft > 0; sft >>= 1) {
        if (t < sft) red[t] += red[t + sft];
        __syncthreads();
    }
    if (t == 0) partials[b] = red[0];
}

// ---------------------------------------------------------------------------
__global__ __launch_bounds__(256)
void k4_reduce(const double* __restrict__ partials, int nPart,
               float* __restrict__ out) {
    __shared__ double red[256];
    const int t = threadIdx.x;
    double s = 0.0;
    for (int i = t; i < nPart; i += 256) s += partials[i];
    red[t] = s;
    __syncthreads();
    for (int sft = 128; sft > 0; sft >>= 1) {
        if (t < sft) red[t] += red[t + sft];
        __syncthreads();
    }
    if (t == 0) out[0] = (float)(red[0] / (double)((long long)NB * DD * HH * WW));
}

// ---------------------------------------------------------------------------
extern "C" void kernel_launch(void* const* d_in, const int* in_sizes, int n_in,
                              void* d_out, int out_size, void* d_ws, size_t ws_size,
                              hipStream_t stream) {
    const float* img1 = (const float*)d_in[0];
    const float* img2 = (const float*)d_in[1];
    float* out = (float*)d_out;

    GW gw;
    {
        double gs[KS], ssum = 0.0;
        for (int i = 0; i < KS; ++i) {
            const double c = (double)(i - KS / 2);
            gs[i] = exp(-c * c / (2.0 * 1.5 * 1.5));
            ssum += gs[i];
        }
        for (int i = 0; i < KS; ++i) gw.g[i] = (float)(gs[i] / ssum);
    }

    const long long FS = (long long)NB * DD * HH * WW;  // 8,388,608
    __half* A = (__half*)d_ws;                          // 5 fields fp16, 84 MB
    double* partials = (double*)((char*)d_ws + 5 * FS * sizeof(__half));

    const int nBlocksK1 = NB * ZCH * 64;   // 2048
    const int nBlocksK2 = NB * DD * 16;    // 8192

    k1_dconv<<<nBlocksK1, 256, 0, stream>>>(img1, img2, A, gw);
    k2_ssim<<<nBlocksK2, 256, 0, stream>>>(A, partials, gw);
    k4_reduce<<<1, 256, 0, stream>>>(partials, nBlocksK2, out);
}

// Round 4
// 97.674 us; speedup vs baseline: 1.8336x; 1.8336x over previous
//
#include <hip/hip_runtime.h>
#include <hip/hip_fp16.h>
#include <math.h>

#define NB  4
#define DD  128
#define HH  128
#define WW  128
#define KS  11
#define PAD 5
#define ZCK 64            // z outputs per K1 block
#define HCK 64            // h outputs per K2 block
#define RW  144           // padded LDS row length (5 + 128 + 5 -> 144)

struct GW { float g[KS]; };

// ---------------------------------------------------------------------------
// K1: fields (x,y,x2,y2,xy) + W-conv + D-conv fused.
// Block = 256 thr (2 h-rows x 128 w), walks z over a 64-plane chunk (+10 warm).
// Per z-step: stage the two raw rows (x,y) in LDS (pads pre-zeroed once),
// W-conv = 11 taps x (2 ds_read + 7 flops) covering ALL 5 fields,
// D-conv = 55-register shift-accumulator chain (static indices only).
// Output A[f][n][z][h][w] fp16. No halo redundancy in w or h.
// ---------------------------------------------------------------------------
__global__ __launch_bounds__(256)
void k1_wd(const float* __restrict__ img1, const float* __restrict__ img2,
           __half* __restrict__ A, GW gw) {
    __shared__ float srow[2][2][RW];   // [img][row][slot]
    const int t  = threadIdx.x;
    const int b  = blockIdx.x;
    const int hb = b & 63;
    const int zc = (b >> 6) & 1;
    const int n  = b >> 7;
    const int r  = t >> 7;
    const int w  = t & 127;
    const int h  = hb * 2 + r;
    const int z0 = zc * ZCK;

    // zero the 5-wide pad slots once (never overwritten)
    if (t < 40) {
        const int grp = t / 10;            // [img<<1 | row]
        const int s10 = t % 10;
        const int slot = (s10 < 5) ? s10 : (WW + PAD + s10 - 5);
        srow[grp >> 1][grp & 1][slot] = 0.f;
    }

    const long long FS      = (long long)NB * DD * HH * WW;
    const long long volBase = (long long)n * DD * HH * WW +
                              (long long)h * WW + w;

    float acc[5][KS];
    #pragma unroll
    for (int f = 0; f < 5; ++f)
        #pragma unroll
        for (int j = 0; j < KS; ++j) acc[f][j] = 0.f;

    // prefetch s = 0 (z_in = z0 - 5; z0-5 >= -5, < DD always)
    float px = 0.f, py = 0.f;
    {
        const int zi = z0 - PAD;
        if (zi >= 0) {
            const long long off = volBase + (long long)zi * (HH * WW);
            px = img1[off];
            py = img2[off];
        }
    }
    __syncthreads();   // pads visible

    const int STEPS = ZCK + 2 * PAD;
    for (int s = 0; s < STEPS; ++s) {
        srow[0][r][PAD + w] = px;
        srow[1][r][PAD + w] = py;

        // prefetch next z-plane
        const int zn = z0 - PAD + s + 1;
        px = 0.f; py = 0.f;
        if (s + 1 < STEPS && zn >= 0 && zn < DD) {
            const long long off = volBase + (long long)zn * (HH * WW);
            px = img1[off];
            py = img2[off];
        }
        __syncthreads();

        float a0 = 0.f, a1 = 0.f, a2 = 0.f, a3 = 0.f, a4 = 0.f;
        #pragma unroll
        for (int k = 0; k < KS; ++k) {
            const float g  = gw.g[k];
            const float xv = srow[0][r][w + k];
            const float yv = srow[1][r][w + k];
            const float gx = g * xv, gy = g * yv;
            a0 += gx;
            a1 += gy;
            a2 = fmaf(gx, xv, a2);
            a3 = fmaf(gy, yv, a3);
            a4 = fmaf(gx, yv, a4);
        }
        __syncthreads();   // reads done before next iteration's writes

        const float v[5] = {a0, a1, a2, a3, a4};
        #pragma unroll
        for (int f = 0; f < 5; ++f) {
            #pragma unroll
            for (int j = KS - 1; j >= 1; --j)
                acc[f][j] = fmaf(gw.g[j], v[f], acc[f][j - 1]);
            acc[f][0] = gw.g[0] * v[f];
        }

        if (s >= 2 * PAD) {
            const int zo = z0 + s - 2 * PAD;
            const long long ooff = volBase + (long long)zo * (HH * WW);
            #pragma unroll
            for (int f = 0; f < 5; ++f)
                A[f * FS + ooff] = __float2half(acc[f][KS - 1]);
        }
    }
}

// ---------------------------------------------------------------------------
// K2: H-conv via register shift chains + SSIM + block reduction. No LDS
// staging; A is L3-resident. Thread owns one (n,z,w) column, walks h over a
// 64-row chunk (+10 warm). 5 fp16 loads + 55 fma per step, 1-step prefetch.
// ---------------------------------------------------------------------------
__global__ __launch_bounds__(256)
void k2_hssim(const __half* __restrict__ A, double* __restrict__ partials,
              GW gw) {
    const int t  = threadIdx.x;
    const int b  = blockIdx.x;
    const int hc = b & 1;
    const int zp = (b >> 1) & 63;
    const int n  = b >> 7;
    const int zl = t >> 7;
    const int w  = t & 127;
    const int z  = zp * 2 + zl;
    const int h0 = hc * HCK;

    const long long FS = (long long)NB * DD * HH * WW;
    const long long colBase = ((long long)(n * DD + z)) * (HH * WW) + w;

    float acc[5][KS];
    #pragma unroll
    for (int f = 0; f < 5; ++f)
        #pragma unroll
        for (int j = 0; j < KS; ++j) acc[f][j] = 0.f;

    // prefetch s = 0 (h_in = h0 - 5)
    __half pf[5];
    #pragma unroll
    for (int f = 0; f < 5; ++f) pf[f] = __float2half(0.f);
    {
        const int hi = h0 - PAD;
        if (hi >= 0) {
            const long long off = colBase + (long long)hi * WW;
            #pragma unroll
            for (int f = 0; f < 5; ++f) pf[f] = A[f * FS + off];
        }
    }

    const float C1 = 1e-4f, C2 = 9e-4f;
    float sum = 0.f;
    const int STEPS = HCK + 2 * PAD;
    for (int s = 0; s < STEPS; ++s) {
        float v[5];
        #pragma unroll
        for (int f = 0; f < 5; ++f) v[f] = __half2float(pf[f]);

        // prefetch next h row
        const int hn = h0 - PAD + s + 1;
        #pragma unroll
        for (int f = 0; f < 5; ++f) pf[f] = __float2half(0.f);
        if (s + 1 < STEPS && hn >= 0 && hn < HH) {
            const long long off = colBase + (long long)hn * WW;
            #pragma unroll
            for (int f = 0; f < 5; ++f) pf[f] = A[f * FS + off];
        }

        #pragma unroll
        for (int f = 0; f < 5; ++f) {
            #pragma unroll
            for (int j = KS - 1; j >= 1; --j)
                acc[f][j] = fmaf(gw.g[j], v[f], acc[f][j - 1]);
            acc[f][0] = gw.g[0] * v[f];
        }

        if (s >= 2 * PAD) {
            const float mu1 = acc[0][KS - 1], mu2 = acc[1][KS - 1];
            const float mu1s = mu1 * mu1, mu2s = mu2 * mu2, mu12 = mu1 * mu2;
            const float sg1  = acc[2][KS - 1] - mu1s;
            const float sg2  = acc[3][KS - 1] - mu2s;
            const float sg12 = acc[4][KS - 1] - mu12;
            const float num = (2.f * mu12 + C1) * (2.f * sg12 + C2);
            const float den = (mu1s + mu2s + C1) * (sg1 + sg2 + C2);
            sum += num / den;
        }
    }

    __shared__ double red[256];
    red[t] = (double)sum;
    __syncthreads();
    for (int sft = 128; sft > 0; sft >>= 1) {
        if (t < sft) red[t] += red[t + sft];
        __syncthreads();
    }
    if (t == 0) partials[b] = red[0];
}

// ---------------------------------------------------------------------------
__global__ __launch_bounds__(256)
void k4_reduce(const double* __restrict__ partials, int nPart,
               float* __restrict__ out) {
    __shared__ double red[256];
    const int t = threadIdx.x;
    double s = 0.0;
    for (int i = t; i < nPart; i += 256) s += partials[i];
    red[t] = s;
    __syncthreads();
    for (int sft = 128; sft > 0; sft >>= 1) {
        if (t < sft) red[t] += red[t + sft];
        __syncthreads();
    }
    if (t == 0) out[0] = (float)(red[0] / (double)((long long)NB * DD * HH * WW));
}

// ---------------------------------------------------------------------------
extern "C" void kernel_launch(void* const* d_in, const int* in_sizes, int n_in,
                              void* d_out, int out_size, void* d_ws, size_t ws_size,
                              hipStream_t stream) {
    const float* img1 = (const float*)d_in[0];
    const float* img2 = (const float*)d_in[1];
    float* out = (float*)d_out;

    GW gw;
    {
        double gs[KS], ssum = 0.0;
        for (int i = 0; i < KS; ++i) {
            const double c = (double)(i - KS / 2);
            gs[i] = exp(-c * c / (2.0 * 1.5 * 1.5));
            ssum += gs[i];
        }
        for (int i = 0; i < KS; ++i) gw.g[i] = (float)(gs[i] / ssum);
    }

    const long long FS = (long long)NB * DD * HH * WW;  // 8,388,608
    __half* A = (__half*)d_ws;                          // 5 fields fp16, 84 MB
    double* partials = (double*)((char*)d_ws + 5 * FS * sizeof(__half));

    const int nBlocksK1 = NB * 64 * (DD / ZCK);   // 512
    const int nBlocksK2 = NB * 64 * (HH / HCK);   // 512

    k1_wd<<<nBlocksK1, 256, 0, stream>>>(img1, img2, A, gw);
    k2_hssim<<<nBlocksK2, 256, 0, stream>>>(A, partials, gw);
    k4_reduce<<<1, 256, 0, stream>>>(partials, nBlocksK2, out);
}

// Round 5
// 84.209 us; speedup vs baseline: 2.1268x; 1.1599x over previous
//
#include <hip/hip_runtime.h>
#include <hip/hip_fp16.h>
#include <math.h>

#define NB  4
#define DD  128
#define HH  128
#define WW  128
#define KS  11
#define PAD 5
#define ZCK 32            // z outputs per K1 block (4 chunks -> 1024 blocks)
#define HCK 32            // h outputs per K2 block (4 chunks -> 1024 blocks)
#define RW  144           // padded LDS row length (5 + 128 + 5 -> 138, pad to 144)

struct GW { float g[KS]; };

// ---------------------------------------------------------------------------
// K1: fields (x,y,x2,y2,xy) + W-conv + D-conv fused.
// Block = 256 thr (2 h-rows x 128 w) walks z over a 32-plane chunk (+10 warm).
// Ping-pong LDS row buffers -> ONE barrier per step; 2-deep global prefetch
// (load for s+2 issued at s). Loop manually unrolled by 2 so every buffer /
// register index is compile-time constant. fp16 stores to A[f][n][z][h][w].
// ---------------------------------------------------------------------------
__global__ __launch_bounds__(256)
void k1_wd(const float* __restrict__ img1, const float* __restrict__ img2,
           __half* __restrict__ A, GW gw) {
    __shared__ float srow[2][2][2][RW];   // [buf][img][row][slot]
    const int t  = threadIdx.x;
    const int b  = blockIdx.x;
    const int hb = b & 63;
    const int zc = (b >> 6) & 3;
    const int n  = b >> 8;
    const int r  = t >> 7;
    const int w  = t & 127;
    const int h  = hb * 2 + r;
    const int z0 = zc * ZCK;

    // zero the 5-wide pad slots once (both buffers, never overwritten)
    if (t < 80) {
        const int grp = t / 10;            // [buf][img][row]
        const int s10 = t % 10;
        const int slot = (s10 < 5) ? s10 : (WW + PAD + s10 - 5);
        srow[grp >> 2][(grp >> 1) & 1][grp & 1][slot] = 0.f;
    }

    const long long FS      = (long long)NB * DD * HH * WW;
    const long long volBase = (long long)n * DD * HH * WW +
                              (long long)h * WW + w;

    float acc[5][KS];
    #pragma unroll
    for (int f = 0; f < 5; ++f)
        #pragma unroll
        for (int j = 0; j < KS; ++j) acc[f][j] = 0.f;

    const int STEPS = ZCK + 2 * PAD;       // 42, even

    // preload planes 0 and 1 (z_in = z0-5, z0-4; can be <0 only, never >=DD)
    float rx0 = 0.f, ry0 = 0.f, rx1 = 0.f, ry1 = 0.f;
    {
        const int zi0 = z0 - PAD;
        if (zi0 >= 0) {
            const long long off = volBase + (long long)zi0 * (HH * WW);
            rx0 = img1[off]; ry0 = img2[off];
        }
        const int zi1 = z0 - PAD + 1;
        if (zi1 >= 0) {
            const long long off = volBase + (long long)zi1 * (HH * WW);
            rx1 = img1[off]; ry1 = img2[off];
        }
    }
    // stage plane 0 into buf 0
    srow[0][0][r][PAD + w] = rx0;
    srow[0][1][r][PAD + w] = ry0;
    __syncthreads();

    #define K1_STEP(S, CUR, NXT, RXC, RYC, RXN, RYN)                          \
    {                                                                          \
        /* issue load plane S+2 -> (RXC,RYC); consumed at step S+1 */          \
        {                                                                      \
            const int zi = z0 - PAD + (S) + 2;                                 \
            float lx = 0.f, ly = 0.f;                                          \
            if ((S) + 2 < STEPS && zi >= 0 && zi < DD) {                       \
                const long long off = volBase + (long long)zi * (HH * WW);     \
                lx = img1[off]; ly = img2[off];                                \
            }                                                                  \
            RXC = lx; RYC = ly;                                                \
        }                                                                      \
        /* W-conv from buf CUR */                                              \
        float a0 = 0.f, a1 = 0.f, a2 = 0.f, a3 = 0.f, a4 = 0.f;                \
        _Pragma("unroll")                                                      \
        for (int k = 0; k < KS; ++k) {                                         \
            const float g  = gw.g[k];                                          \
            const float xv = srow[CUR][0][r][w + k];                           \
            const float yv = srow[CUR][1][r][w + k];                           \
            const float gx = g * xv, gy = g * yv;                              \
            a0 += gx;                                                          \
            a1 += gy;                                                          \
            a2 = fmaf(gx, xv, a2);                                             \
            a3 = fmaf(gy, yv, a3);                                             \
            a4 = fmaf(gx, yv, a4);                                             \
        }                                                                      \
        /* stage plane S+1 into buf NXT (waits on its load here) */            \
        srow[NXT][0][r][PAD + w] = RXN;                                        \
        srow[NXT][1][r][PAD + w] = RYN;                                        \
        __syncthreads();                                                       \
        /* D-conv shift-accumulator chains */                                  \
        const float v[5] = {a0, a1, a2, a3, a4};                               \
        _Pragma("unroll")                                                      \
        for (int f = 0; f < 5; ++f) {                                          \
            _Pragma("unroll")                                                  \
            for (int j = KS - 1; j >= 1; --j)                                  \
                acc[f][j] = fmaf(gw.g[j], v[f], acc[f][j - 1]);                \
            acc[f][0] = gw.g[0] * v[f];                                        \
        }                                                                      \
        if ((S) >= 2 * PAD) {                                                  \
            const int zo = z0 + (S) - 2 * PAD;                                 \
            const long long ooff = volBase + (long long)zo * (HH * WW);        \
            _Pragma("unroll")                                                  \
            for (int f = 0; f < 5; ++f)                                        \
                A[f * FS + ooff] = __float2half(acc[f][KS - 1]);               \
        }                                                                      \
    }

    for (int s2 = 0; s2 < STEPS; s2 += 2) {
        K1_STEP(s2,     0, 1, rx0, ry0, rx1, ry1)
        K1_STEP(s2 + 1, 1, 0, rx1, ry1, rx0, ry0)
    }
    #undef K1_STEP
}

// ---------------------------------------------------------------------------
// K2: H-conv via register shift chains + SSIM + block reduction. No LDS
// staging; A is L3-resident. Thread owns one (n,z,w) column, walks h over a
// 32-row chunk (+10 warm). 5 fp16 loads + 55 fma per step, 1-step prefetch.
// ---------------------------------------------------------------------------
__global__ __launch_bounds__(256)
void k2_hssim(const __half* __restrict__ A, double* __restrict__ partials,
              GW gw) {
    const int t  = threadIdx.x;
    const int b  = blockIdx.x;
    const int hc = b & 3;
    const int zp = (b >> 2) & 63;
    const int n  = b >> 8;
    const int zl = t >> 7;
    const int w  = t & 127;
    const int z  = zp * 2 + zl;
    const int h0 = hc * HCK;

    const long long FS = (long long)NB * DD * HH * WW;
    const long long colBase = ((long long)(n * DD + z)) * (HH * WW) + w;

    float acc[5][KS];
    #pragma unroll
    for (int f = 0; f < 5; ++f)
        #pragma unroll
        for (int j = 0; j < KS; ++j) acc[f][j] = 0.f;

    // prefetch s = 0 (h_in = h0 - 5)
    __half pf[5];
    #pragma unroll
    for (int f = 0; f < 5; ++f) pf[f] = __float2half(0.f);
    {
        const int hi = h0 - PAD;
        if (hi >= 0) {
            const long long off = colBase + (long long)hi * WW;
            #pragma unroll
            for (int f = 0; f < 5; ++f) pf[f] = A[f * FS + off];
        }
    }

    const float C1 = 1e-4f, C2 = 9e-4f;
    float sum = 0.f;
    const int STEPS = HCK + 2 * PAD;
    for (int s = 0; s < STEPS; ++s) {
        float v[5];
        #pragma unroll
        for (int f = 0; f < 5; ++f) v[f] = __half2float(pf[f]);

        // prefetch next h row
        const int hn = h0 - PAD + s + 1;
        #pragma unroll
        for (int f = 0; f < 5; ++f) pf[f] = __float2half(0.f);
        if (s + 1 < STEPS && hn >= 0 && hn < HH) {
            const long long off = colBase + (long long)hn * WW;
            #pragma unroll
            for (int f = 0; f < 5; ++f) pf[f] = A[f * FS + off];
        }

        #pragma unroll
        for (int f = 0; f < 5; ++f) {
            #pragma unroll
            for (int j = KS - 1; j >= 1; --j)
                acc[f][j] = fmaf(gw.g[j], v[f], acc[f][j - 1]);
            acc[f][0] = gw.g[0] * v[f];
        }

        if (s >= 2 * PAD) {
            const float mu1 = acc[0][KS - 1], mu2 = acc[1][KS - 1];
            const float mu1s = mu1 * mu1, mu2s = mu2 * mu2, mu12 = mu1 * mu2;
            const float sg1  = acc[2][KS - 1] - mu1s;
            const float sg2  = acc[3][KS - 1] - mu2s;
            const float sg12 = acc[4][KS - 1] - mu12;
            const float num = (2.f * mu12 + C1) * (2.f * sg12 + C2);
            const float den = (mu1s + mu2s + C1) * (sg1 + sg2 + C2);
            sum += num / den;
        }
    }

    __shared__ double red[256];
    red[t] = (double)sum;
    __syncthreads();
    for (int sft = 128; sft > 0; sft >>= 1) {
        if (t < sft) red[t] += red[t + sft];
        __syncthreads();
    }
    if (t == 0) partials[b] = red[0];
}

// ---------------------------------------------------------------------------
__global__ __launch_bounds__(256)
void k4_reduce(const double* __restrict__ partials, int nPart,
               float* __restrict__ out) {
    __shared__ double red[256];
    const int t = threadIdx.x;
    double s = 0.0;
    for (int i = t; i < nPart; i += 256) s += partials[i];
    red[t] = s;
    __syncthreads();
    for (int sft = 128; sft > 0; sft >>= 1) {
        if (t < sft) red[t] += red[t + sft];
        __syncthreads();
    }
    if (t == 0) out[0] = (float)(red[0] / (double)((long long)NB * DD * HH * WW));
}

// ---------------------------------------------------------------------------
extern "C" void kernel_launch(void* const* d_in, const int* in_sizes, int n_in,
                              void* d_out, int out_size, void* d_ws, size_t ws_size,
                              hipStream_t stream) {
    const float* img1 = (const float*)d_in[0];
    const float* img2 = (const float*)d_in[1];
    float* out = (float*)d_out;

    GW gw;
    {
        double gs[KS], ssum = 0.0;
        for (int i = 0; i < KS; ++i) {
            const double c = (double)(i - KS / 2);
            gs[i] = exp(-c * c / (2.0 * 1.5 * 1.5));
            ssum += gs[i];
        }
        for (int i = 0; i < KS; ++i) gw.g[i] = (float)(gs[i] / ssum);
    }

    const long long FS = (long long)NB * DD * HH * WW;  // 8,388,608
    __half* A = (__half*)d_ws;                          // 5 fields fp16, 84 MB
    double* partials = (double*)((char*)d_ws + 5 * FS * sizeof(__half));

    const int nBlocksK1 = NB * 64 * (DD / ZCK);   // 1024
    const int nBlocksK2 = NB * 64 * (HH / HCK);   // 1024

    k1_wd<<<nBlocksK1, 256, 0, stream>>>(img1, img2, A, gw);
    k2_hssim<<<nBlocksK2, 256, 0, stream>>>(A, partials, gw);
    k4_reduce<<<1, 256, 0, stream>>>(partials, nBlocksK2, out);
}

// Round 6
// 68.229 us; speedup vs baseline: 2.6249x; 1.2342x over previous
//
#include <hip/hip_runtime.h>
#include <hip/hip_fp16.h>
#include <math.h>

#define NB  4
#define DD  128
#define HH  128
#define WW  128
#define KS  11
#define PAD 5
#define NF  4             // fields: xbar, ybar, xybar, (x2+y2)bar
#define ZCK 32            // z outputs per K1 block (4 chunks -> 1024 blocks)
#define HCK 32            // h outputs per K2 block (4 chunks -> 1024 blocks)
#define RW  144           // padded LDS row length

struct GW { float g[KS]; };

// Layout: A[n][z][h][f][w] fp16 -> per-voxel field stores/loads share ONE
// address with immediate offsets f*WW*2 bytes (256/512/768 B, < 4KB imm).
#define ZSTRIDE (HH * NF * WW)   // 65536 halfs per z plane
#define HSTRIDE (NF * WW)        // 512 halfs per h row

// ---------------------------------------------------------------------------
// K1: fields + W-conv (symmetric taps) + D-conv fused.
// Block = 256 thr (2 h-rows x 128 w) walks z over a 32-plane chunk (+10 warm).
// Ping-pong LDS row buffers (1 barrier/step), 2-deep global prefetch,
// manually unrolled by 2 (all buffer/register indices compile-time).
// Warmup (10 steps, no store) and main (32 steps, store) loops split.
// ---------------------------------------------------------------------------
__global__ __launch_bounds__(256)
void k1_wd(const float* __restrict__ img1, const float* __restrict__ img2,
           __half* __restrict__ A, GW gw) {
    __shared__ float srow[2][2][2][RW];   // [buf][img][row][slot]
    const int t  = threadIdx.x;
    const int b  = blockIdx.x;
    const int hb = b & 63;
    const int zc = (b >> 6) & 3;
    const int n  = b >> 8;
    const int r  = t >> 7;
    const int w  = t & 127;
    const int h  = hb * 2 + r;
    const int z0 = zc * ZCK;

    if (t < 80) {   // zero the 5-wide pad slots once
        const int grp = t / 10;
        const int s10 = t % 10;
        const int slot = (s10 < 5) ? s10 : (WW + PAD + s10 - 5);
        srow[grp >> 2][(grp >> 1) & 1][grp & 1][slot] = 0.f;
    }

    const long long inBase = (long long)n * DD * HH * WW +
                             (long long)h * WW + w;                 // fp32 vol
    const long long outBase = (long long)n * DD * ZSTRIDE +
                              (long long)h * HSTRIDE + w;           // fp16 A

    float acc[NF][KS];
    #pragma unroll
    for (int f = 0; f < NF; ++f)
        #pragma unroll
        for (int j = 0; j < KS; ++j) acc[f][j] = 0.f;

    const int STEPS = ZCK + 2 * PAD;   // 42

    float rx0 = 0.f, ry0 = 0.f, rx1 = 0.f, ry1 = 0.f;
    {
        const int zi0 = z0 - PAD;
        if (zi0 >= 0) {
            const long long off = inBase + (long long)zi0 * (HH * WW);
            rx0 = img1[off]; ry0 = img2[off];
        }
        const int zi1 = z0 - PAD + 1;
        if (zi1 >= 0) {
            const long long off = inBase + (long long)zi1 * (HH * WW);
            rx1 = img1[off]; ry1 = img2[off];
        }
    }
    srow[0][0][r][PAD + w] = rx0;
    srow[0][1][r][PAD + w] = ry0;
    __syncthreads();

    #define K1_STEP(S, CUR, NXT, RXC, RYC, RXN, RYN, DOST)                     \
    {                                                                          \
        {   /* issue load plane S+2 into the regs freed this step */           \
            const int zi = z0 - PAD + (S) + 2;                                 \
            float lx = 0.f, ly = 0.f;                                          \
            if ((S) + 2 < STEPS && zi >= 0 && zi < DD) {                       \
                const long long off = inBase + (long long)zi * (HH * WW);      \
                lx = img1[off]; ly = img2[off];                                \
            }                                                                  \
            RXC = lx; RYC = ly;                                                \
        }                                                                      \
        /* W-conv (symmetric pairs) from buf CUR */                            \
        float a0 = 0.f, a1 = 0.f, a2 = 0.f, a3 = 0.f;                          \
        _Pragma("unroll")                                                      \
        for (int k = 0; k < 5; ++k) {                                          \
            const float g  = gw.g[k];                                          \
            const float x0 = srow[CUR][0][r][w + k];                           \
            const float x1 = srow[CUR][0][r][w + 10 - k];                      \
            const float y0 = srow[CUR][1][r][w + k];                           \
            const float y1 = srow[CUR][1][r][w + 10 - k];                      \
            a0 = fmaf(g, x0 + x1, a0);                                         \
            a1 = fmaf(g, y0 + y1, a1);                                         \
            const float pxy = fmaf(x1, y1, x0 * y0);                           \
            a2 = fmaf(g, pxy, a2);                                             \
            float pss = x0 * x0;                                               \
            pss = fmaf(x1, x1, pss);                                           \
            pss = fmaf(y0, y0, pss);                                           \
            pss = fmaf(y1, y1, pss);                                           \
            a3 = fmaf(g, pss, a3);                                             \
        }                                                                      \
        {                                                                      \
            const float g = gw.g[5];                                           \
            const float x = srow[CUR][0][r][w + 5];                            \
            const float y = srow[CUR][1][r][w + 5];                            \
            a0 = fmaf(g, x, a0);                                               \
            a1 = fmaf(g, y, a1);                                               \
            a2 = fmaf(g, x * y, a2);                                           \
            const float ps = fmaf(y, y, x * x);                                \
            a3 = fmaf(g, ps, a3);                                              \
        }                                                                      \
        /* stage plane S+1 into buf NXT */                                     \
        srow[NXT][0][r][PAD + w] = RXN;                                        \
        srow[NXT][1][r][PAD + w] = RYN;                                        \
        __syncthreads();                                                       \
        /* D-conv shift-accumulator chains */                                  \
        const float v[NF] = {a0, a1, a2, a3};                                  \
        _Pragma("unroll")                                                      \
        for (int f = 0; f < NF; ++f) {                                         \
            _Pragma("unroll")                                                  \
            for (int j = KS - 1; j >= 1; --j)                                  \
                acc[f][j] = fmaf(gw.g[j], v[f], acc[f][j - 1]);                \
            acc[f][0] = gw.g[0] * v[f];                                        \
        }                                                                      \
        if (DOST) {                                                            \
            const int zo = z0 + (S) - 2 * PAD;                                 \
            __half* op = A + outBase + (long long)zo * ZSTRIDE;                \
            op[0 * WW] = __float2half(acc[0][KS - 1]);                         \
            op[1 * WW] = __float2half(acc[1][KS - 1]);                         \
            op[2 * WW] = __float2half(acc[2][KS - 1]);                         \
            op[3 * WW] = __float2half(acc[3][KS - 1]);                         \
        }                                                                      \
    }

    for (int s2 = 0; s2 < 2 * PAD; s2 += 2) {          // warmup, no store
        K1_STEP(s2,     0, 1, rx0, ry0, rx1, ry1, 0)
        K1_STEP(s2 + 1, 1, 0, rx1, ry1, rx0, ry0, 0)
    }
    for (int s2 = 2 * PAD; s2 < STEPS; s2 += 2) {      // main, store
        K1_STEP(s2,     0, 1, rx0, ry0, rx1, ry1, 1)
        K1_STEP(s2 + 1, 1, 0, rx1, ry1, rx0, ry0, 1)
    }
    #undef K1_STEP
}

// ---------------------------------------------------------------------------
// K2: H-conv via register shift chains + SSIM + block reduction. No LDS
// staging (A is L3-resident). Thread owns one (n,z,w) column, walks h over a
// 32-row chunk (+10 warm). 4 fp16 loads share one address (imm offsets),
// 2-deep prefetch, unrolled by 2, rcp+NR division.
// ---------------------------------------------------------------------------
__global__ __launch_bounds__(256)
void k2_hssim(const __half* __restrict__ A, double* __restrict__ partials,
              GW gw) {
    const int t  = threadIdx.x;
    const int b  = blockIdx.x;
    const int hc = b & 3;
    const int zp = (b >> 2) & 63;
    const int n  = b >> 8;
    const int zl = t >> 7;
    const int w  = t & 127;
    const int z  = zp * 2 + zl;
    const int h0 = hc * HCK;

    const long long colBase = ((long long)(n * DD + z)) * ZSTRIDE + w;

    float acc[NF][KS];
    #pragma unroll
    for (int f = 0; f < NF; ++f)
        #pragma unroll
        for (int j = 0; j < KS; ++j) acc[f][j] = 0.f;

    const int STEPS = HCK + 2 * PAD;   // 42

    __half pfA[NF], pfB[NF];
    #pragma unroll
    for (int f = 0; f < NF; ++f) { pfA[f] = __float2half(0.f); pfB[f] = pfA[f]; }
    {
        const int hi0 = h0 - PAD;
        if (hi0 >= 0) {
            const __half* p = A + colBase + (long long)hi0 * HSTRIDE;
            #pragma unroll
            for (int f = 0; f < NF; ++f) pfA[f] = p[f * WW];
        }
        const int hi1 = h0 - PAD + 1;
        if (hi1 >= 0) {
            const __half* p = A + colBase + (long long)hi1 * HSTRIDE;
            #pragma unroll
            for (int f = 0; f < NF; ++f) pfB[f] = p[f * WW];
        }
    }

    const float C1 = 1e-4f, C2 = 9e-4f;
    float sum = 0.f;

    #define K2_STEP(S, PFC, DOSSIM)                                            \
    {                                                                          \
        float v[NF];                                                           \
        _Pragma("unroll")                                                      \
        for (int f = 0; f < NF; ++f) v[f] = __half2float(PFC[f]);              \
        {   /* prefetch row S+2 into PFC */                                    \
            const int hi = h0 - PAD + (S) + 2;                                 \
            _Pragma("unroll")                                                  \
            for (int f = 0; f < NF; ++f) PFC[f] = __float2half(0.f);           \
            if ((S) + 2 < STEPS && hi >= 0 && hi < HH) {                       \
                const __half* p = A + colBase + (long long)hi * HSTRIDE;       \
                _Pragma("unroll")                                              \
                for (int f = 0; f < NF; ++f) PFC[f] = p[f * WW];               \
            }                                                                  \
        }                                                                      \
        _Pragma("unroll")                                                      \
        for (int f = 0; f < NF; ++f) {                                         \
            _Pragma("unroll")                                                  \
            for (int j = KS - 1; j >= 1; --j)                                  \
                acc[f][j] = fmaf(gw.g[j], v[f], acc[f][j - 1]);                \
            acc[f][0] = gw.g[0] * v[f];                                        \
        }                                                                      \
        if (DOSSIM) {                                                          \
            const float mu1 = acc[0][KS - 1], mu2 = acc[1][KS - 1];            \
            const float mu1s = mu1 * mu1, mu2s = mu2 * mu2, mu12 = mu1 * mu2;  \
            const float sg12 = acc[2][KS - 1] - mu12;                          \
            const float sgss = acc[3][KS - 1] - mu1s - mu2s;                   \
            const float num = (2.f * mu12 + C1) * (2.f * sg12 + C2);           \
            const float den = (mu1s + mu2s + C1) * (sgss + C2);                \
            float rr = __builtin_amdgcn_rcpf(den);                             \
            rr = rr * fmaf(-den, rr, 2.0f);   /* 1 NR step */                  \
            sum = fmaf(num, rr, sum);                                          \
        }                                                                      \
    }

    for (int s2 = 0; s2 < 2 * PAD; s2 += 2) {
        K2_STEP(s2,     pfA, 0)
        K2_STEP(s2 + 1, pfB, 0)
    }
    for (int s2 = 2 * PAD; s2 < STEPS; s2 += 2) {
        K2_STEP(s2,     pfA, 1)
        K2_STEP(s2 + 1, pfB, 1)
    }
    #undef K2_STEP

    __shared__ double red[256];
    red[t] = (double)sum;
    __syncthreads();
    for (int sft = 128; sft > 0; sft >>= 1) {
        if (t < sft) red[t] += red[t + sft];
        __syncthreads();
    }
    if (t == 0) partials[b] = red[0];
}

// ---------------------------------------------------------------------------
__global__ __launch_bounds__(256)
void k4_reduce(const double* __restrict__ partials, int nPart,
               float* __restrict__ out) {
    __shared__ double red[256];
    const int t = threadIdx.x;
    double s = 0.0;
    for (int i = t; i < nPart; i += 256) s += partials[i];
    red[t] = s;
    __syncthreads();
    for (int sft = 128; sft > 0; sft >>= 1) {
        if (t < sft) red[t] += red[t + sft];
        __syncthreads();
    }
    if (t == 0) out[0] = (float)(red[0] / (double)((long long)NB * DD * HH * WW));
}

// ---------------------------------------------------------------------------
extern "C" void kernel_launch(void* const* d_in, const int* in_sizes, int n_in,
                              void* d_out, int out_size, void* d_ws, size_t ws_size,
                              hipStream_t stream) {
    const float* img1 = (const float*)d_in[0];
    const float* img2 = (const float*)d_in[1];
    float* out = (float*)d_out;

    GW gw;
    {
        double gs[KS], ssum = 0.0;
        for (int i = 0; i < KS; ++i) {
            const double c = (double)(i - KS / 2);
            gs[i] = exp(-c * c / (2.0 * 1.5 * 1.5));
            ssum += gs[i];
        }
        for (int i = 0; i < KS; ++i) gw.g[i] = (float)(gs[i] / ssum);
    }

    __half* A = (__half*)d_ws;   // [n][z][h][f][w] fp16, 67 MB
    double* partials =
        (double*)((char*)d_ws + (long long)NB * DD * ZSTRIDE * sizeof(__half));

    const int nBlocksK1 = NB * 64 * (DD / ZCK);   // 1024
    const int nBlocksK2 = NB * 64 * (HH / HCK);   // 1024

    k1_wd<<<nBlocksK1, 256, 0, stream>>>(img1, img2, A, gw);
    k2_hssim<<<nBlocksK2, 256, 0, stream>>>(A, partials, gw);
    k4_reduce<<<1, 256, 0, stream>>>(partials, nBlocksK2, out);
}

// Round 7
// 60.645 us; speedup vs baseline: 2.9532x; 1.1251x over previous
//
#include <hip/hip_runtime.h>
#include <hip/hip_fp16.h>
#include <math.h>

#define NB  4
#define DD  128
#define HH  128
#define WW  128
#define KS  11
#define PAD 5
#define NF  4             // fields: xbar, ybar, xybar, (x2+y2)bar
#define ZCK 32            // z outputs per K1 block
#define HCK 32            // h outputs per K2 block
#define RW  144           // padded LDS row length (floats)
#define LOFF 6            // w-coord u lives at LDS slot LOFF+u (keeps b64 align)

using f32x2 = __attribute__((ext_vector_type(2))) float;

struct GW { float g[KS]; };

static __device__ __forceinline__ f32x2 vfma2(f32x2 a, f32x2 b, f32x2 c) {
    return __builtin_elementwise_fma(a, b, c);
}

// Layout: A[n][z][h][f][w] fp16; per-voxel-pair field access shares one
// address with immediate offsets f*WW*2 bytes.
#define ZSTRIDE (HH * NF * WW)   // halfs per z plane
#define HSTRIDE (NF * WW)        // halfs per h row

// ---------------------------------------------------------------------------
// K1: fields + W-conv + D-conv fused, 2 w-voxels per thread.
// Block = 256 thr = 4 h-rows x 64 w-pairs, walks z over 32 planes (+10 warm).
// Ping-pong LDS rows (1 barrier/step), 2-deep float2 prefetch, unroll-by-2.
// D-chains are f32x2 (packed fp32 fma). fp16x2 stores.
// ---------------------------------------------------------------------------
__global__ __launch_bounds__(256)
void k1_wd(const float* __restrict__ img1, const float* __restrict__ img2,
           __half* __restrict__ A, GW gw) {
    __shared__ alignas(16) float srow[2][2][4][RW];   // [buf][img][row][slot]
    const int t  = threadIdx.x;
    const int b  = blockIdx.x;
    const int hb = b & 31;
    const int zc = (b >> 5) & 3;
    const int n  = b >> 7;
    const int r  = t >> 6;        // h-row 0..3
    const int q  = t & 63;        // w-pair
    const int w0 = q * 2;
    const int h  = hb * 4 + r;
    const int z0 = zc * ZCK;

    // zero pad slots once: w-coords -6..-1 (slots 0..5), 128..133 (134..139)
    if (t < 192) {
        const int grp = t / 12, s12 = t % 12;
        const int slot = (s12 < 6) ? s12 : (128 + s12);
        srow[grp >> 3][(grp >> 2) & 1][grp & 3][slot] = 0.f;
    }

    const long long inBase  = (long long)n * DD * HH * WW +
                              (long long)h * WW + w0;
    const long long outBase = (long long)n * DD * ZSTRIDE +
                              (long long)h * HSTRIDE + w0;

    f32x2 acc[NF][KS];
    #pragma unroll
    for (int f = 0; f < NF; ++f)
        #pragma unroll
        for (int j = 0; j < KS; ++j) acc[f][j] = (f32x2){0.f, 0.f};

    const int STEPS = ZCK + 2 * PAD;   // 42

    float2 rx0 = make_float2(0.f, 0.f), ry0 = rx0, rx1 = rx0, ry1 = rx0;
    {
        const int zi0 = z0 - PAD;
        if (zi0 >= 0) {
            const long long off = inBase + (long long)zi0 * (HH * WW);
            rx0 = *(const float2*)(img1 + off);
            ry0 = *(const float2*)(img2 + off);
        }
        const int zi1 = z0 - PAD + 1;
        if (zi1 >= 0) {
            const long long off = inBase + (long long)zi1 * (HH * WW);
            rx1 = *(const float2*)(img1 + off);
            ry1 = *(const float2*)(img2 + off);
        }
    }
    *(float2*)&srow[0][0][r][LOFF + w0] = rx0;
    *(float2*)&srow[0][1][r][LOFF + w0] = ry0;
    __syncthreads();

    // element e (0..13) = w-coord w0-6+e = slot w0+e
    #define ELV(A2, i) ((i) & 1 ? A2[(i) >> 1].y : A2[(i) >> 1].x)

    #define K1_STEP(S, CUR, NXT, RXC, RYC, RXN, RYN, DOST)                     \
    {                                                                          \
        {   /* issue load of plane S+2 into the regs freed last step */       \
            const int zi = z0 - PAD + (S) + 2;                                 \
            float2 lx = make_float2(0.f, 0.f), ly = lx;                        \
            if ((S) + 2 < STEPS && zi >= 0 && zi < DD) {                       \
                const long long off = inBase + (long long)zi * (HH * WW);      \
                lx = *(const float2*)(img1 + off);                             \
                ly = *(const float2*)(img2 + off);                             \
            }                                                                  \
            RXC = lx; RYC = ly;                                                \
        }                                                                      \
        /* load 14 values per image from buf CUR (7 x ds_read_b64) */          \
        f32x2 xv2[7], yv2[7];                                                  \
        _Pragma("unroll")                                                      \
        for (int i = 0; i < 7; ++i) {                                          \
            const float2 ax = *(const float2*)&srow[CUR][0][r][w0 + 2 * i];    \
            const float2 ay = *(const float2*)&srow[CUR][1][r][w0 + 2 * i];    \
            xv2[i] = (f32x2){ax.x, ax.y};                                      \
            yv2[i] = (f32x2){ay.x, ay.y};                                      \
        }                                                                      \
        /* packed products shared by both voxels */                            \
        f32x2 pv2[7], qv2[7];                                                  \
        _Pragma("unroll")                                                      \
        for (int i = 0; i < 7; ++i) {                                          \
            pv2[i] = xv2[i] * yv2[i];                                          \
            qv2[i] = vfma2(yv2[i], yv2[i], xv2[i] * xv2[i]);                   \
        }                                                                      \
        /* W-conv: vox0 uses elements k+1, vox1 uses k+2 */                    \
        float a0x = 0.f, a0y = 0.f, a1x = 0.f, a1y = 0.f;                      \
        float a2x = 0.f, a2y = 0.f, a3x = 0.f, a3y = 0.f;                      \
        _Pragma("unroll")                                                      \
        for (int k = 0; k < KS; ++k) {                                         \
            const float g = gw.g[k];                                           \
            a0x = fmaf(g, ELV(xv2, k + 1), a0x);                               \
            a0y = fmaf(g, ELV(xv2, k + 2), a0y);                               \
            a1x = fmaf(g, ELV(yv2, k + 1), a1x);                               \
            a1y = fmaf(g, ELV(yv2, k + 2), a1y);                               \
            a2x = fmaf(g, ELV(pv2, k + 1), a2x);                               \
            a2y = fmaf(g, ELV(pv2, k + 2), a2y);                               \
            a3x = fmaf(g, ELV(qv2, k + 1), a3x);                               \
            a3y = fmaf(g, ELV(qv2, k + 2), a3y);                               \
        }                                                                      \
        /* stage plane S+1 into buf NXT */                                     \
        *(float2*)&srow[NXT][0][r][LOFF + w0] = RXN;                           \
        *(float2*)&srow[NXT][1][r][LOFF + w0] = RYN;                           \
        __syncthreads();                                                       \
        /* packed D-conv shift-accumulator chains */                           \
        f32x2 v[NF];                                                           \
        v[0] = (f32x2){a0x, a0y}; v[1] = (f32x2){a1x, a1y};                    \
        v[2] = (f32x2){a2x, a2y}; v[3] = (f32x2){a3x, a3y};                    \
        _Pragma("unroll")                                                      \
        for (int f = 0; f < NF; ++f) {                                         \
            _Pragma("unroll")                                                  \
            for (int j = KS - 1; j >= 1; --j) {                                \
                const f32x2 gg = {gw.g[j], gw.g[j]};                           \
                acc[f][j] = vfma2(gg, v[f], acc[f][j - 1]);                    \
            }                                                                  \
            const f32x2 g0 = {gw.g[0], gw.g[0]};                               \
            acc[f][0] = g0 * v[f];                                             \
        }                                                                      \
        if (DOST) {                                                            \
            const int zo = z0 + (S) - 2 * PAD;                                 \
            __half* op = A + outBase + (long long)zo * ZSTRIDE;                \
            *(__half2*)(op + 0 * WW) =                                         \
                __float22half2_rn(make_float2(acc[0][KS-1].x, acc[0][KS-1].y));\
            *(__half2*)(op + 1 * WW) =                                         \
                __float22half2_rn(make_float2(acc[1][KS-1].x, acc[1][KS-1].y));\
            *(__half2*)(op + 2 * WW) =                                         \
                __float22half2_rn(make_float2(acc[2][KS-1].x, acc[2][KS-1].y));\
            *(__half2*)(op + 3 * WW) =                                         \
                __float22half2_rn(make_float2(acc[3][KS-1].x, acc[3][KS-1].y));\
        }                                                                      \
    }

    for (int s2 = 0; s2 < 2 * PAD; s2 += 2) {          // warmup, no store
        K1_STEP(s2,     0, 1, rx0, ry0, rx1, ry1, 0)
        K1_STEP(s2 + 1, 1, 0, rx1, ry1, rx0, ry0, 0)
    }
    for (int s2 = 2 * PAD; s2 < STEPS; s2 += 2) {      // main, store
        K1_STEP(s2,     0, 1, rx0, ry0, rx1, ry1, 1)
        K1_STEP(s2 + 1, 1, 0, rx1, ry1, rx0, ry0, 1)
    }
    #undef K1_STEP
    #undef ELV
}

// ---------------------------------------------------------------------------
// K2: H-conv (packed f32x2 shift chains) + packed SSIM + block reduction.
// 2 w-voxels per thread; 4 half2 loads per step share one address; 2-deep
// prefetch; rcp+NR division. No LDS staging (A is L2/L3-resident).
// Block = 256 thr = 4 z-rows x 64 w-pairs, walks h over 32 rows (+10 warm).
// ---------------------------------------------------------------------------
__global__ __launch_bounds__(256)
void k2_hssim(const __half* __restrict__ A, double* __restrict__ partials,
              GW gw) {
    const int t  = threadIdx.x;
    const int b  = blockIdx.x;
    const int hc = b & 3;
    const int zp = (b >> 2) & 31;
    const int n  = b >> 7;
    const int zl = t >> 6;
    const int q  = t & 63;
    const int w0 = q * 2;
    const int z  = zp * 4 + zl;
    const int h0 = hc * HCK;

    const long long colBase = ((long long)(n * DD + z)) * ZSTRIDE + w0;

    f32x2 acc[NF][KS];
    #pragma unroll
    for (int f = 0; f < NF; ++f)
        #pragma unroll
        for (int j = 0; j < KS; ++j) acc[f][j] = (f32x2){0.f, 0.f};

    const int STEPS = HCK + 2 * PAD;   // 42

    unsigned pfA[NF] = {0u, 0u, 0u, 0u};
    unsigned pfB[NF] = {0u, 0u, 0u, 0u};
    {
        const int hi0 = h0 - PAD;
        if (hi0 >= 0) {
            const __half* p = A + colBase + (long long)hi0 * HSTRIDE;
            #pragma unroll
            for (int f = 0; f < NF; ++f) pfA[f] = *(const unsigned*)(p + f * WW);
        }
        const int hi1 = h0 - PAD + 1;
        if (hi1 >= 0) {
            const __half* p = A + colBase + (long long)hi1 * HSTRIDE;
            #pragma unroll
            for (int f = 0; f < NF; ++f) pfB[f] = *(const unsigned*)(p + f * WW);
        }
    }

    const f32x2 C1v = {1e-4f, 1e-4f}, C2v = {9e-4f, 9e-4f};
    const f32x2 TWO = {2.f, 2.f};
    f32x2 sum = {0.f, 0.f};

    #define K2_STEP(S, PFC, DOSSIM)                                            \
    {                                                                          \
        f32x2 v[NF];                                                           \
        _Pragma("unroll")                                                      \
        for (int f = 0; f < NF; ++f) {                                         \
            const float2 fv = __half22float2(*(const __half2*)&PFC[f]);        \
            v[f] = (f32x2){fv.x, fv.y};                                        \
        }                                                                      \
        {   /* prefetch row S+2 */                                             \
            const int hi = h0 - PAD + (S) + 2;                                 \
            _Pragma("unroll")                                                  \
            for (int f = 0; f < NF; ++f) PFC[f] = 0u;                          \
            if ((S) + 2 < STEPS && hi >= 0 && hi < HH) {                       \
                const __half* p = A + colBase + (long long)hi * HSTRIDE;       \
                _Pragma("unroll")                                              \
                for (int f = 0; f < NF; ++f)                                   \
                    PFC[f] = *(const unsigned*)(p + f * WW);                   \
            }                                                                  \
        }                                                                      \
        _Pragma("unroll")                                                      \
        for (int f = 0; f < NF; ++f) {                                         \
            _Pragma("unroll")                                                  \
            for (int j = KS - 1; j >= 1; --j) {                                \
                const f32x2 gg = {gw.g[j], gw.g[j]};                           \
                acc[f][j] = vfma2(gg, v[f], acc[f][j - 1]);                    \
            }                                                                  \
            const f32x2 g0 = {gw.g[0], gw.g[0]};                               \
            acc[f][0] = g0 * v[f];                                             \
        }                                                                      \
        if (DOSSIM) {                                                          \
            const f32x2 mu1 = acc[0][KS - 1], mu2 = acc[1][KS - 1];            \
            const f32x2 mu1s = mu1 * mu1, mu2s = mu2 * mu2, mu12 = mu1 * mu2;  \
            const f32x2 sg12 = acc[2][KS - 1] - mu12;                          \
            const f32x2 sgss = acc[3][KS - 1] - mu1s - mu2s;                   \
            const f32x2 num = vfma2(TWO, mu12, C1v) * vfma2(TWO, sg12, C2v);   \
            const f32x2 den = (mu1s + mu2s + C1v) * (sgss + C2v);              \
            f32x2 rr;                                                          \
            rr.x = __builtin_amdgcn_rcpf(den.x);                               \
            rr.y = __builtin_amdgcn_rcpf(den.y);                               \
            rr = rr * vfma2(-den, rr, TWO);   /* 1 NR step */                  \
            sum = vfma2(num, rr, sum);                                         \
        }                                                                      \
    }

    for (int s2 = 0; s2 < 2 * PAD; s2 += 2) {
        K2_STEP(s2,     pfA, 0)
        K2_STEP(s2 + 1, pfB, 0)
    }
    for (int s2 = 2 * PAD; s2 < STEPS; s2 += 2) {
        K2_STEP(s2,     pfA, 1)
        K2_STEP(s2 + 1, pfB, 1)
    }
    #undef K2_STEP

    __shared__ double red[256];
    red[t] = (double)sum.x + (double)sum.y;
    __syncthreads();
    for (int sft = 128; sft > 0; sft >>= 1) {
        if (t < sft) red[t] += red[t + sft];
        __syncthreads();
    }
    if (t == 0) partials[b] = red[0];
}

// ---------------------------------------------------------------------------
__global__ __launch_bounds__(256)
void k4_reduce(const double* __restrict__ partials, int nPart,
               float* __restrict__ out) {
    __shared__ double red[256];
    const int t = threadIdx.x;
    double s = 0.0;
    for (int i = t; i < nPart; i += 256) s += partials[i];
    red[t] = s;
    __syncthreads();
    for (int sft = 128; sft > 0; sft >>= 1) {
        if (t < sft) red[t] += red[t + sft];
        __syncthreads();
    }
    if (t == 0) out[0] = (float)(red[0] / (double)((long long)NB * DD * HH * WW));
}

// ---------------------------------------------------------------------------
extern "C" void kernel_launch(void* const* d_in, const int* in_sizes, int n_in,
                              void* d_out, int out_size, void* d_ws, size_t ws_size,
                              hipStream_t stream) {
    const float* img1 = (const float*)d_in[0];
    const float* img2 = (const float*)d_in[1];
    float* out = (float*)d_out;

    GW gw;
    {
        double gs[KS], ssum = 0.0;
        for (int i = 0; i < KS; ++i) {
            const double c = (double)(i - KS / 2);
            gs[i] = exp(-c * c / (2.0 * 1.5 * 1.5));
            ssum += gs[i];
        }
        for (int i = 0; i < KS; ++i) gw.g[i] = (float)(gs[i] / ssum);
    }

    __half* A = (__half*)d_ws;   // [n][z][h][f][w] fp16, 67 MB
    double* partials =
        (double*)((char*)d_ws + (long long)NB * DD * ZSTRIDE * sizeof(__half));

    const int nBlocksK1 = NB * 32 * (DD / ZCK);   // 512
    const int nBlocksK2 = NB * 32 * (HH / HCK);   // 512

    k1_wd<<<nBlocksK1, 256, 0, stream>>>(img1, img2, A, gw);
    k2_hssim<<<nBlocksK2, 256, 0, stream>>>(A, partials, gw);
    k4_reduce<<<1, 256, 0, stream>>>(partials, nBlocksK2, out);
}

// Round 9
// 58.274 us; speedup vs baseline: 3.0734x; 1.0407x over previous
//
#include <hip/hip_runtime.h>
#include <hip/hip_fp16.h>
#include <math.h>

#define NB  4
#define DD  128
#define HH  128
#define WW  128
#define KS  11
#define PAD 5
#define NF  4             // fields: xbar, ybar, xybar, (x2+y2)bar
#define ZCK 32            // z outputs per K1 block
#define HCK 32            // h outputs per K2 block
#define RW  144           // padded LDS row length (floats)
#define LOFF 6            // w-coord u lives at LDS slot LOFF+u

// Packed intermediate layout: A[n][z][h][q][f*2] fp16 (q = w-pair).
// One 16B vector holds all 4 fields for a w-pair -> 1 load/store per voxel-pair.
#define QS      8                 // halfs per q-slot (4 fields x 2 voxels)
#define HROW    (64 * QS)         // 512 halfs per h row
#define ZPLANE  (HH * HROW)       // 65536 halfs per z plane

using f32x2 = __attribute__((ext_vector_type(2))) float;

struct GW { float g[KS]; };

static __device__ __forceinline__ f32x2 vfma2(f32x2 a, f32x2 b, f32x2 c) {
    return __builtin_elementwise_fma(a, b, c);
}
static __device__ __forceinline__ unsigned h2u(__half2 v) {
    union { __half2 h; unsigned u; } x; x.h = v; return x.u;
}
static __device__ __forceinline__ f32x2 u2f2(unsigned u) {
    union { unsigned u; __half2 h; } x; x.u = u;
    const float2 f = __half22float2(x.h);
    return (f32x2){f.x, f.y};
}

// Wave-local LDS ordering fence: compile-time memory barrier + lgkm drain.
// Does NOT touch vmcnt (global prefetch stays in flight), does NOT sync waves.
#define WAVE_LDS_FENCE() asm volatile("s_waitcnt lgkmcnt(0)" ::: "memory")

// ---------------------------------------------------------------------------
// K1: fields + W-conv + D-conv fused, 2 w-voxels per thread. BARRIER-FREE:
// each wave owns one h-row and touches only its own LDS slice. Cross-lane
// write->read ordering inside the wave is enforced by WAVE_LDS_FENCE() at the
// top of each step (the compiler's per-lane alias model would otherwise be
// free to reorder next-step ds_reads above this step's ds_writes).
// Ping-pong LDS rows, 2-deep float2 prefetch, unroll-by-2, packed f32x2
// D-chains, single dwordx4 store per step (all 4 fields).
// Block = 256 thr = 4 waves = 4 h-rows x 64 w-pairs; walks 32 z (+10 warm).
// ---------------------------------------------------------------------------
__global__ __launch_bounds__(256)
void k1_wd(const float* __restrict__ img1, const float* __restrict__ img2,
           __half* __restrict__ A, GW gw) {
    __shared__ alignas(16) float srow[2][2][4][RW];   // [buf][img][row][slot]
    const int t  = threadIdx.x;
    const int b  = blockIdx.x;
    const int hb = b & 31;
    const int zc = (b >> 5) & 3;
    const int n  = b >> 7;
    const int r  = t >> 6;        // h-row == wave id
    const int q  = t & 63;        // w-pair == lane
    const int w0 = q * 2;
    const int h  = hb * 4 + r;
    const int z0 = zc * ZCK;

    // wave-local pad init: lanes 0..47 zero this wave's 2x2x12 pad slots
    if (q < 48) {
        const int grp = q / 12, s12 = q % 12;      // grp = [buf][img]
        const int slot = (s12 < 6) ? s12 : (128 + s12);
        srow[grp >> 1][grp & 1][r][slot] = 0.f;
    }

    const long long inBase  = (long long)n * DD * HH * WW +
                              (long long)h * WW + w0;
    const long long outBase = (long long)n * DD * ZPLANE +
                              (long long)h * HROW + (long long)q * QS;

    f32x2 acc[NF][KS];
    #pragma unroll
    for (int f = 0; f < NF; ++f)
        #pragma unroll
        for (int j = 0; j < KS; ++j) acc[f][j] = (f32x2){0.f, 0.f};

    const int STEPS = ZCK + 2 * PAD;   // 42

    float2 rx0 = make_float2(0.f, 0.f), ry0 = rx0, rx1 = rx0, ry1 = rx0;
    {
        const int zi0 = z0 - PAD;
        if (zi0 >= 0) {
            const long long off = inBase + (long long)zi0 * (HH * WW);
            rx0 = *(const float2*)(img1 + off);
            ry0 = *(const float2*)(img2 + off);
        }
        const int zi1 = z0 - PAD + 1;
        if (zi1 >= 0) {
            const long long off = inBase + (long long)zi1 * (HH * WW);
            rx1 = *(const float2*)(img1 + off);
            ry1 = *(const float2*)(img2 + off);
        }
    }
    *(float2*)&srow[0][0][r][LOFF + w0] = rx0;
    *(float2*)&srow[0][1][r][LOFF + w0] = ry0;
    // no block barrier: wave-local data only; fence at top of each step

    // element e (0..13) = w-coord w0-6+e = slot w0+e
    #define ELV(A2, i) ((i) & 1 ? A2[(i) >> 1].y : A2[(i) >> 1].x)

    #define K1_STEP(S, CUR, NXT, RXC, RYC, RXN, RYN, DOST)                     \
    {                                                                          \
        /* order previous step's ds_writes before this step's ds_reads */      \
        WAVE_LDS_FENCE();                                                      \
        {   /* issue load of plane S+2 into the regs freed last step */        \
            const int zi = z0 - PAD + (S) + 2;                                 \
            float2 lx = make_float2(0.f, 0.f), ly = lx;                        \
            if ((S) + 2 < STEPS && zi >= 0 && zi < DD) {                       \
                const long long off = inBase + (long long)zi * (HH * WW);      \
                lx = *(const float2*)(img1 + off);                             \
                ly = *(const float2*)(img2 + off);                             \
            }                                                                  \
            RXC = lx; RYC = ly;                                                \
        }                                                                      \
        /* load 14 values per image from buf CUR (7 x ds_read_b64 each) */     \
        f32x2 xv2[7], yv2[7];                                                  \
        _Pragma("unroll")                                                      \
        for (int i = 0; i < 7; ++i) {                                          \
            const float2 ax = *(const float2*)&srow[CUR][0][r][w0 + 2 * i];    \
            const float2 ay = *(const float2*)&srow[CUR][1][r][w0 + 2 * i];    \
            xv2[i] = (f32x2){ax.x, ax.y};                                      \
            yv2[i] = (f32x2){ay.x, ay.y};                                      \
        }                                                                      \
        /* packed products shared by both voxels */                            \
        f32x2 pv2[7], qv2[7];                                                  \
        _Pragma("unroll")                                                      \
        for (int i = 0; i < 7; ++i) {                                          \
            pv2[i] = xv2[i] * yv2[i];                                          \
            qv2[i] = vfma2(yv2[i], yv2[i], xv2[i] * xv2[i]);                   \
        }                                                                      \
        /* W-conv: vox0 uses elements k+1, vox1 uses k+2 */                    \
        float a0x = 0.f, a0y = 0.f, a1x = 0.f, a1y = 0.f;                      \
        float a2x = 0.f, a2y = 0.f, a3x = 0.f, a3y = 0.f;                      \
        _Pragma("unroll")                                                      \
        for (int k = 0; k < KS; ++k) {                                         \
            const float g = gw.g[k];                                           \
            a0x = fmaf(g, ELV(xv2, k + 1), a0x);                               \
            a0y = fmaf(g, ELV(xv2, k + 2), a0y);                               \
            a1x = fmaf(g, ELV(yv2, k + 1), a1x);                               \
            a1y = fmaf(g, ELV(yv2, k + 2), a1y);                               \
            a2x = fmaf(g, ELV(pv2, k + 1), a2x);                               \
            a2y = fmaf(g, ELV(pv2, k + 2), a2y);                               \
            a3x = fmaf(g, ELV(qv2, k + 1), a3x);                               \
            a3y = fmaf(g, ELV(qv2, k + 2), a3y);                               \
        }                                                                      \
        /* stage plane S+1 into buf NXT (wave-local; fenced next step) */      \
        *(float2*)&srow[NXT][0][r][LOFF + w0] = RXN;                           \
        *(float2*)&srow[NXT][1][r][LOFF + w0] = RYN;                           \
        /* packed D-conv shift-accumulator chains */                           \
        f32x2 v[NF];                                                           \
        v[0] = (f32x2){a0x, a0y}; v[1] = (f32x2){a1x, a1y};                    \
        v[2] = (f32x2){a2x, a2y}; v[3] = (f32x2){a3x, a3y};                    \
        _Pragma("unroll")                                                      \
        for (int f = 0; f < NF; ++f) {                                         \
            _Pragma("unroll")                                                  \
            for (int j = KS - 1; j >= 1; --j) {                                \
                const f32x2 gg = {gw.g[j], gw.g[j]};                           \
                acc[f][j] = vfma2(gg, v[f], acc[f][j - 1]);                    \
            }                                                                  \
            const f32x2 g0 = {gw.g[0], gw.g[0]};                               \
            acc[f][0] = g0 * v[f];                                             \
        }                                                                      \
        if (DOST) {                                                            \
            const int zo = z0 + (S) - 2 * PAD;                                 \
            uint4 pk;                                                          \
            pk.x = h2u(__float22half2_rn(                                      \
                       make_float2(acc[0][KS-1].x, acc[0][KS-1].y)));          \
            pk.y = h2u(__float22half2_rn(                                      \
                       make_float2(acc[1][KS-1].x, acc[1][KS-1].y)));          \
            pk.z = h2u(__float22half2_rn(                                      \
                       make_float2(acc[2][KS-1].x, acc[2][KS-1].y)));          \
            pk.w = h2u(__float22half2_rn(                                      \
                       make_float2(acc[3][KS-1].x, acc[3][KS-1].y)));          \
            *(uint4*)(A + outBase + (long long)zo * ZPLANE) = pk;              \
        }                                                                      \
    }

    for (int s2 = 0; s2 < 2 * PAD; s2 += 2) {          // warmup, no store
        K1_STEP(s2,     0, 1, rx0, ry0, rx1, ry1, 0)
        K1_STEP(s2 + 1, 1, 0, rx1, ry1, rx0, ry0, 0)
    }
    for (int s2 = 2 * PAD; s2 < STEPS; s2 += 2) {      // main, store
        K1_STEP(s2,     0, 1, rx0, ry0, rx1, ry1, 1)
        K1_STEP(s2 + 1, 1, 0, rx1, ry1, rx0, ry0, 1)
    }
    #undef K1_STEP
    #undef ELV
}

// ---------------------------------------------------------------------------
// K2: H-conv (packed f32x2 shift chains) + packed SSIM + block reduction.
// 2 w-voxels per thread; ONE dwordx4 load per step delivers all 4 fields;
// 2-deep prefetch; rcp+NR division. No LDS staging (A is L2/L3-resident).
// Block = 256 thr = 4 z-rows x 64 w-pairs, walks h over 32 rows (+10 warm).
// ---------------------------------------------------------------------------
__global__ __launch_bounds__(256)
void k2_hssim(const __half* __restrict__ A, double* __restrict__ partials,
              GW gw) {
    const int t  = threadIdx.x;
    const int b  = blockIdx.x;
    const int hc = b & 3;
    const int zp = (b >> 2) & 31;
    const int n  = b >> 7;
    const int zl = t >> 6;
    const int q  = t & 63;
    const int z  = zp * 4 + zl;
    const int h0 = hc * HCK;

    const long long colBase =
        ((long long)(n * DD + z)) * ZPLANE + (long long)q * QS;

    f32x2 acc[NF][KS];
    #pragma unroll
    for (int f = 0; f < NF; ++f)
        #pragma unroll
        for (int j = 0; j < KS; ++j) acc[f][j] = (f32x2){0.f, 0.f};

    const int STEPS = HCK + 2 * PAD;   // 42

    uint4 pfA = make_uint4(0u, 0u, 0u, 0u), pfB = pfA;
    {
        const int hi0 = h0 - PAD;
        if (hi0 >= 0)
            pfA = *(const uint4*)(A + colBase + (long long)hi0 * HROW);
        const int hi1 = h0 - PAD + 1;
        if (hi1 >= 0)
            pfB = *(const uint4*)(A + colBase + (long long)hi1 * HROW);
    }

    const f32x2 C1v = {1e-4f, 1e-4f}, C2v = {9e-4f, 9e-4f};
    const f32x2 TWO = {2.f, 2.f};
    f32x2 sum = {0.f, 0.f};

    #define K2_STEP(S, PFC, DOSSIM)                                            \
    {                                                                          \
        f32x2 v[NF];                                                           \
        v[0] = u2f2(PFC.x); v[1] = u2f2(PFC.y);                                \
        v[2] = u2f2(PFC.z); v[3] = u2f2(PFC.w);                                \
        {   /* prefetch row S+2 */                                             \
            const int hi = h0 - PAD + (S) + 2;                                 \
            uint4 nv = make_uint4(0u, 0u, 0u, 0u);                             \
            if ((S) + 2 < STEPS && hi >= 0 && hi < HH)                         \
                nv = *(const uint4*)(A + colBase + (long long)hi * HROW);      \
            PFC = nv;                                                          \
        }                                                                      \
        _Pragma("unroll")                                                      \
        for (int f = 0; f < NF; ++f) {                                         \
            _Pragma("unroll")                                                  \
            for (int j = KS - 1; j >= 1; --j) {                                \
                const f32x2 gg = {gw.g[j], gw.g[j]};                           \
                acc[f][j] = vfma2(gg, v[f], acc[f][j - 1]);                    \
            }                                                                  \
            const f32x2 g0 = {gw.g[0], gw.g[0]};                               \
            acc[f][0] = g0 * v[f];                                             \
        }                                                                      \
        if (DOSSIM) {                                                          \
            const f32x2 mu1 = acc[0][KS - 1], mu2 = acc[1][KS - 1];            \
            const f32x2 mu1s = mu1 * mu1, mu2s = mu2 * mu2, mu12 = mu1 * mu2;  \
            const f32x2 sg12 = acc[2][KS - 1] - mu12;                          \
            const f32x2 sgss = acc[3][KS - 1] - mu1s - mu2s;                   \
            const f32x2 num = vfma2(TWO, mu12, C1v) * vfma2(TWO, sg12, C2v);   \
            const f32x2 den = (mu1s + mu2s + C1v) * (sgss + C2v);              \
            f32x2 rr;                                                          \
            rr.x = __builtin_amdgcn_rcpf(den.x);                               \
            rr.y = __builtin_amdgcn_rcpf(den.y);                               \
            rr = rr * vfma2(-den, rr, TWO);   /* 1 NR step */                  \
            sum = vfma2(num, rr, sum);                                         \
        }                                                                      \
    }

    for (int s2 = 0; s2 < 2 * PAD; s2 += 2) {
        K2_STEP(s2,     pfA, 0)
        K2_STEP(s2 + 1, pfB, 0)
    }
    for (int s2 = 2 * PAD; s2 < STEPS; s2 += 2) {
        K2_STEP(s2,     pfA, 1)
        K2_STEP(s2 + 1, pfB, 1)
    }
    #undef K2_STEP

    __shared__ double red[256];
    red[t] = (double)sum.x + (double)sum.y;
    __syncthreads();
    for (int sft = 128; sft > 0; sft >>= 1) {
        if (t < sft) red[t] += red[t + sft];
        __syncthreads();
    }
    if (t == 0) partials[b] = red[0];
}

// ---------------------------------------------------------------------------
__global__ __launch_bounds__(256)
void k4_reduce(const double* __restrict__ partials, int nPart,
               float* __restrict__ out) {
    __shared__ double red[256];
    const int t = threadIdx.x;
    double s = 0.0;
    for (int i = t; i < nPart; i += 256) s += partials[i];
    red[t] = s;
    __syncthreads();
    for (int sft = 128; sft > 0; sft >>= 1) {
        if (t < sft) red[t] += red[t + sft];
        __syncthreads();
    }
    if (t == 0) out[0] = (float)(red[0] / (double)((long long)NB * DD * HH * WW));
}

// ---------------------------------------------------------------------------
extern "C" void kernel_launch(void* const* d_in, const int* in_sizes, int n_in,
                              void* d_out, int out_size, void* d_ws, size_t ws_size,
                              hipStream_t stream) {
    const float* img1 = (const float*)d_in[0];
    const float* img2 = (const float*)d_in[1];
    float* out = (float*)d_out;

    GW gw;
    {
        double gs[KS], ssum = 0.0;
        for (int i = 0; i < KS; ++i) {
            const double c = (double)(i - KS / 2);
            gs[i] = exp(-c * c / (2.0 * 1.5 * 1.5));
            ssum += gs[i];
        }
        for (int i = 0; i < KS; ++i) gw.g[i] = (float)(gs[i] / ssum);
    }

    __half* A = (__half*)d_ws;   // [n][z][h][q][f*2] fp16, 67 MB
    double* partials =
        (double*)((char*)d_ws + (long long)NB * DD * ZPLANE * sizeof(__half));

    const int nBlocksK1 = NB * 32 * (DD / ZCK);   // 512
    const int nBlocksK2 = NB * 32 * (HH / HCK);   // 512

    k1_wd<<<nBlocksK1, 256, 0, stream>>>(img1, img2, A, gw);
    k2_hssim<<<nBlocksK2, 256, 0, stream>>>(A, partials, gw);
    k4_reduce<<<1, 256, 0, stream>>>(partials, nBlocksK2, out);
}